// Round 4
// baseline (556.422 us; speedup 1.0000x reference)
//
#include <hip/hip_runtime.h>

// -------------------- helpers --------------------
static __device__ __forceinline__ float4 ld4(const float* p) { return *(const float4*)p; }

// XCD-stripe bin for a dst node: 512-node stripes round-robin over 8 bins.
static __device__ __forceinline__ int dbin(int d) { return (d >> 9) & 7; }

// -------------------- binning pass: partition edges by dst-stripe bin --------------------
// Appends (src,dst) and ew contiguously into per-bin segments (capE each).
__global__ __launch_bounds__(256) void k_bin(const int* __restrict__ src,
                                             const int* __restrict__ dst,
                                             const float* __restrict__ ew,
                                             int* __restrict__ bin_cnt,
                                             int2* __restrict__ ebuf,
                                             float* __restrict__ ewb,
                                             int E, int capE) {
    __shared__ int h[8];
    __shared__ int basee[8];
    int tid = threadIdx.x;
    if (tid < 8) h[tid] = 0;
    __syncthreads();
    int e = blockIdx.x * 256 + tid;
    int s = 0, d = 0, b = 0, loc = 0; float w = 0.f;
    bool act = e < E;
    if (act) {
        s = src[e]; d = dst[e]; w = ew[e];
        b = dbin(d);
        loc = atomicAdd(&h[b], 1);
    }
    __syncthreads();
    if (tid < 8) basee[tid] = atomicAdd(&bin_cnt[tid], h[tid]);
    __syncthreads();
    if (act) {
        int p = b * capE + basee[b] + loc;
        ebuf[p] = make_int2(s, d);
        ewb[p] = w;
    }
}

// -------------------- histogram over binned edges: packed u64 atomic, XCD-local --------------------
__global__ __launch_bounds__(256) void k_count2(const int2* __restrict__ ebuf,
                                                const float* __restrict__ ewb,
                                                const int* __restrict__ bin_cnt,
                                                unsigned long long* __restrict__ agg,
                                                int capE) {
    int b = blockIdx.x & 7;
    int i = (blockIdx.x >> 3) * 256 + threadIdx.x;
    if (i < bin_cnt[b]) {
        int2 sd = ebuf[(size_t)b * capE + i];
        float w = ewb[(size_t)b * capE + i];
        unsigned long long c = (1ull << 40) |
                               (unsigned long long)(w * 4294967296.0f);
        atomicAdd(&agg[sd.y], c);
    }
}

// -------------------- unpack agg: cnt, dinv; zero fill --------------------
__global__ __launch_bounds__(256) void k_reduce(const unsigned long long* __restrict__ agg,
                                                int* __restrict__ cnt,
                                                int* __restrict__ fill,
                                                float* __restrict__ dinv, int n) {
    int i = blockIdx.x * 256 + threadIdx.x;
    if (i >= n) return;
    unsigned long long v = agg[i];
    cnt[i] = (int)(v >> 40);
    fill[i] = 0;
    float s = (float)(v & ((1ull << 40) - 1)) * (1.0f / 4294967296.0f);
    dinv[i] = rsqrtf(1.0f + s);   // self-loop weight 1 => deg >= 1
}

// -------------------- 3-phase exclusive scan over cnt -> rowptr --------------------
__global__ __launch_bounds__(256) void k_scan_local(const int* __restrict__ cnt,
                                                    int* __restrict__ rowptr,
                                                    int* __restrict__ bsum, int n) {
    __shared__ int s[256];
    int tid = threadIdx.x;
    int i = blockIdx.x * 256 + tid;
    int v = (i < n) ? cnt[i] : 0;
    s[tid] = v; __syncthreads();
    #pragma unroll
    for (int off = 1; off < 256; off <<= 1) {
        int t = (tid >= off) ? s[tid - off] : 0;
        __syncthreads();
        s[tid] += t;
        __syncthreads();
    }
    if (i < n) rowptr[i] = s[tid] - v;
    if (tid == 255) bsum[blockIdx.x] = s[255];
}

__global__ __launch_bounds__(256) void k_scan_bsum(int* bsum, int nb) {
    __shared__ int s[256];
    __shared__ int run;
    int tid = threadIdx.x;
    if (tid == 0) run = 0;
    __syncthreads();
    for (int base = 0; base < nb; base += 256) {
        int v = (base + tid < nb) ? bsum[base + tid] : 0;
        s[tid] = v; __syncthreads();
        #pragma unroll
        for (int off = 1; off < 256; off <<= 1) {
            int t = (tid >= off) ? s[tid - off] : 0;
            __syncthreads();
            s[tid] += t;
            __syncthreads();
        }
        if (base + tid < nb) bsum[base + tid] = run + s[tid] - v;
        __syncthreads();
        if (tid == 0) run += s[255];
        __syncthreads();
    }
}

__global__ __launch_bounds__(256) void k_scan_add(int* __restrict__ rowptr,
                                                  const int* __restrict__ bsum, int n) {
    int i = blockIdx.x * 256 + threadIdx.x;
    if (i < n) rowptr[i] += bsum[blockIdx.x];
}

// -------------------- scatter binned edges into CSR, XCD-local window --------------------
__global__ __launch_bounds__(256) void k_scatter2(const int2* __restrict__ ebuf,
                                                  const float* __restrict__ ewb,
                                                  const int* __restrict__ bin_cnt,
                                                  const float* __restrict__ dinv,
                                                  const int* __restrict__ rowptr,
                                                  int* fill,
                                                  unsigned long long* __restrict__ csr,
                                                  int capE) {
    int b = blockIdx.x & 7;
    int i = (blockIdx.x >> 3) * 256 + threadIdx.x;
    if (i < bin_cnt[b]) {
        int2 sd = ebuf[(size_t)b * capE + i];
        float w = ewb[(size_t)b * capE + i];
        int p = rowptr[sd.y] + atomicAdd(&fill[sd.y], 1);
        float norm = dinv[sd.x] * w * dinv[sd.y];
        csr[p] = (unsigned long long)(unsigned)sd.x |
                 ((unsigned long long)__float_as_uint(norm) << 32);
    }
}

// -------------------- GEMM: out[n,64] = A[n,K] @ W[K,64] --------------------
template<int K, bool SPLITW>
__global__ __launch_bounds__(256) void k_gemm(const float* __restrict__ A,
                                              const float* __restrict__ W0,
                                              const float* __restrict__ W1s,
                                              float* __restrict__ out, int n) {
    __shared__ float Ws[K * 64];
    __shared__ float Xs[64 * K];
    int tid = threadIdx.x;
    int row0 = blockIdx.x * 64;

    constexpr int WF4 = K * 64 / 4;
    for (int j = tid; j < WF4; j += 256) {
        float4 v;
        if (!SPLITW) {
            v = ld4(W0 + j * 4);
        } else {
            int k = (j * 4) >> 6;
            int c = (j * 4) & 63;
            v = (c < 32) ? ld4(W0 + k * 32 + c) : ld4(W1s + k * 32 + (c - 32));
        }
        *(float4*)&Ws[j * 4] = v;
    }
    constexpr int XF4PR = K / 4;
    for (int j = tid; j < 64 * XF4PR; j += 256) {
        int r = j / XF4PR, kc = j % XF4PR;
        int grow = row0 + r;
        float4 v = make_float4(0.f, 0.f, 0.f, 0.f);
        if (grow < n) v = ld4(A + (size_t)grow * K + kc * 4);
        *(float4*)&Xs[r * K + kc * 4] = v;
    }
    __syncthreads();

    int c0 = (tid & 15) * 4;
    int r0 = (tid >> 4) * 4;
    float4 acc[4] = {};
    #pragma unroll 4
    for (int kk = 0; kk < K; kk += 4) {
        float4 w0 = ld4(&Ws[(kk + 0) * 64 + c0]);
        float4 w1 = ld4(&Ws[(kk + 1) * 64 + c0]);
        float4 w2 = ld4(&Ws[(kk + 2) * 64 + c0]);
        float4 w3 = ld4(&Ws[(kk + 3) * 64 + c0]);
        #pragma unroll
        for (int i = 0; i < 4; i++) {
            float4 a = ld4(&Xs[(r0 + i) * K + kk]);
            acc[i].x = fmaf(a.x, w0.x, fmaf(a.y, w1.x, fmaf(a.z, w2.x, fmaf(a.w, w3.x, acc[i].x))));
            acc[i].y = fmaf(a.x, w0.y, fmaf(a.y, w1.y, fmaf(a.z, w2.y, fmaf(a.w, w3.y, acc[i].y))));
            acc[i].z = fmaf(a.x, w0.z, fmaf(a.y, w1.z, fmaf(a.z, w2.z, fmaf(a.w, w3.z, acc[i].z))));
            acc[i].w = fmaf(a.x, w0.w, fmaf(a.y, w1.w, fmaf(a.z, w2.w, fmaf(a.w, w3.w, acc[i].w))));
        }
    }
    #pragma unroll
    for (int i = 0; i < 4; i++) {
        int grow = row0 + r0 + i;
        if (grow < n) *(float4*)&out[(size_t)grow * 64 + c0] = acc[i];
    }
}

// -------------------- propagation (gather over packed CSR), one wave per node --------------------
template<bool RELU, bool SPLIT_OUT>
__global__ __launch_bounds__(256) void k_prop(const float* __restrict__ hin,
                                              const int2* __restrict__ csr,
                                              const int* __restrict__ rowptr,
                                              const int* __restrict__ cnt,
                                              const float* __restrict__ dinv,
                                              const float* __restrict__ bias0,
                                              const float* __restrict__ bias1,
                                              float* __restrict__ out, int n) {
    int node = blockIdx.x * 4 + (threadIdx.x >> 6);
    int c = threadIdx.x & 63;
    if (node >= n) return;
    float di = dinv[node];
    float acc = hin[(size_t)node * 64 + c] * di * di;   // self-loop, weight 1
    const int2* ep = csr + rowptr[node];
    int m = cnt[node];
    int e = 0;
    for (; e + 4 <= m; e += 4) {
        int2 p0 = ep[e], p1 = ep[e + 1], p2 = ep[e + 2], p3 = ep[e + 3];
        acc = fmaf(hin[(size_t)p0.x * 64 + c], __int_as_float(p0.y), acc);
        acc = fmaf(hin[(size_t)p1.x * 64 + c], __int_as_float(p1.y), acc);
        acc = fmaf(hin[(size_t)p2.x * 64 + c], __int_as_float(p2.y), acc);
        acc = fmaf(hin[(size_t)p3.x * 64 + c], __int_as_float(p3.y), acc);
    }
    for (; e < m; e++) {
        int2 p = ep[e];
        acc = fmaf(hin[(size_t)p.x * 64 + c], __int_as_float(p.y), acc);
    }
    if (!SPLIT_OUT) {
        acc += bias0[c];
        if (RELU) acc = fmaxf(acc, 0.0f);
        out[(size_t)node * 64 + c] = acc;
    } else {
        if (c < 32) out[(size_t)node * 32 + c] = acc + bias0[c];
        else        out[(size_t)n * 32 + (size_t)node * 32 + (c - 32)] = acc + bias1[c - 32];
    }
}

// -------------------- launch --------------------
extern "C" void kernel_launch(void* const* d_in, const int* in_sizes, int n_in,
                              void* d_out, int out_size, void* d_ws, size_t ws_size,
                              hipStream_t stream) {
    const float* x   = (const float*)d_in[0];
    const int*   ei  = (const int*)d_in[1];   // [2, E]
    const float* ew  = (const float*)d_in[2];
    const float* W1  = (const float*)d_in[3];
    const float* b1  = (const float*)d_in[4];
    const float* Wmu = (const float*)d_in[5];
    const float* bmu = (const float*)d_in[6];
    const float* Wlv = (const float*)d_in[7];
    const float* blv = (const float*)d_in[8];
    float* outp = (float*)d_out;

    const int n = in_sizes[0] / 128;
    const int E = in_sizes[2];
    const int* src = ei;
    const int* dst = ei + E;
    const int capE = E / 8 + 32768;   // uniform dst: bins ~E/8 (+19+ sigma slack)

    // workspace layout
    size_t o = 0;
    auto alloc = [&](size_t bytes) { void* p = (char*)d_ws + o; o += (bytes + 511) & ~(size_t)511; return p; };
    size_t zbeg = o;
    unsigned long long* agg = (unsigned long long*)alloc((size_t)n * 8);   // memset 0
    int*   bin_cnt  = (int*)alloc(8 * 4);                                  // memset 0
    size_t zend = o;
    int*   fill     = (int*)alloc((size_t)n * 4);                          // zeroed in k_reduce
    int*   cnt      = (int*)alloc((size_t)n * 4);
    float* dinv     = (float*)alloc((size_t)n * 4);
    int*   rowptr   = (int*)alloc((size_t)n * 4);
    int*   bsum     = (int*)alloc((size_t)((n + 255) / 256) * 4);
    unsigned long long* csr = (unsigned long long*)alloc((size_t)E * 8);
    // union region: [ebuf | ewb] (dead after k_scatter2) overlaid with [h0 | h]
    float* h0  = (float*)alloc((size_t)n * 64 * 4);
    float* h   = (float*)alloc((size_t)n * 64 * 4);
    int2*  ebuf = (int2*)h0;                          // 8*capE*8 B  <= 2*n*64*4 for these sizes
    float* ewb  = (float*)((char*)h0 + (size_t)8 * capE * 8);
    float* hc  = h0;   // reuse for fused mu|lv gemm output (h0 dead after prop1)

    const int nb_n = (n + 255) / 256;
    const int nb_e = (E + 255) / 256;
    const int nb_bin = ((capE + 255) / 256) * 8;

    hipMemsetAsync((char*)d_ws + zbeg, 0, zend - zbeg, stream);
    k_bin<<<nb_e, 256, 0, stream>>>(src, dst, ew, bin_cnt, ebuf, ewb, E, capE);
    k_count2<<<nb_bin, 256, 0, stream>>>(ebuf, ewb, bin_cnt, agg, capE);
    k_reduce<<<nb_n, 256, 0, stream>>>(agg, cnt, fill, dinv, n);
    k_scan_local<<<nb_n, 256, 0, stream>>>(cnt, rowptr, bsum, n);
    k_scan_bsum<<<1, 256, 0, stream>>>(bsum, nb_n);
    k_scan_add<<<nb_n, 256, 0, stream>>>(rowptr, bsum, n);
    k_scatter2<<<nb_bin, 256, 0, stream>>>(ebuf, ewb, bin_cnt, dinv, rowptr, fill, csr, capE);

    const int gb = (n + 63) / 64;
    k_gemm<128, false><<<gb, 256, 0, stream>>>(x, W1, nullptr, h0, n);
    k_prop<true, false><<<(n + 3) / 4, 256, 0, stream>>>(h0, (const int2*)csr, rowptr, cnt, dinv,
                                                         b1, nullptr, h, n);
    k_gemm<64, true><<<gb, 256, 0, stream>>>(h, Wmu, Wlv, hc, n);
    k_prop<false, true><<<(n + 3) / 4, 256, 0, stream>>>(hc, (const int2*)csr, rowptr, cnt, dinv,
                                                         bmu, blv, outp, n);
}

// Round 5
// 372.721 us; speedup vs baseline: 1.4929x; 1.4929x over previous
//
#include <hip/hip_runtime.h>

// -------------------- helpers --------------------
static __device__ __forceinline__ float4 ld4(const float* p) { return *(const float4*)p; }

#define NPB 512              // nodes per bin (pow2: ld = d & 511, bin = d >> 9)
#define MAXNB 512            // scan width upper bound for bins

// -------------------- pass 1: partition edges into dst bins --------------------
// 1024 threads x 4 edges. LDS histogram over NB bins -> NB global atomics/block.
// Appends (src,dst) + ew contiguously per bin (runs ~4096/NB edges -> coalesced).
__global__ __launch_bounds__(1024) void k_bin(const int* __restrict__ src,
                                              const int* __restrict__ dst,
                                              const float* __restrict__ ew,
                                              int* __restrict__ bin_cnt,
                                              int2* __restrict__ ebuf,
                                              float* __restrict__ ewb,
                                              int E, int capE, int NB) {
    extern __shared__ int sh[];          // [NB] hist, then [NB] base
    int* h = sh;
    int* base = sh + NB;
    int tid = threadIdx.x;
    for (int j = tid; j < NB; j += 1024) h[j] = 0;
    __syncthreads();
    int e0 = blockIdx.x * 4096;
    int s[4], b[4], loc[4]; float w[4]; bool act[4];
    #pragma unroll
    for (int i = 0; i < 4; i++) {
        int e = e0 + i * 1024 + tid;
        act[i] = e < E;
        if (act[i]) {
            s[i] = src[e];
            int d = dst[e];
            w[i] = ew[e];
            b[i] = d >> 9;
            loc[i] = atomicAdd(&h[b[i]], 1);
            s[i] = s[i];
            // stash dst in high part? keep separate array
            // store d via reuse: pack into loc? simpler: recompute from b & store low bits
            // we need full d for ebuf; keep in w? No - add array:
            b[i] |= (d & 511) << 16;   // pack local-id into b
        }
    }
    __syncthreads();
    for (int j = tid; j < NB; j += 1024) base[j] = atomicAdd(&bin_cnt[j], h[j]);
    __syncthreads();
    #pragma unroll
    for (int i = 0; i < 4; i++) {
        if (act[i]) {
            int bin = b[i] & 0xFFFF;
            int d = (bin << 9) | (b[i] >> 16);
            size_t p = (size_t)bin * capE + base[bin] + loc[i];
            ebuf[p] = make_int2(s[i], d);
            ewb[p] = w[i];
        }
    }
}

// -------------------- pass 2: per-bin count/ewsum (LDS atomics) -> cnt, rowptr, dinv ----------
__global__ __launch_bounds__(512) void k_csr_count(const int2* __restrict__ ebuf,
                                                   const float* __restrict__ ewb,
                                                   const int* __restrict__ bin_cnt,
                                                   int* __restrict__ cnt_g,
                                                   int* __restrict__ rowptr,
                                                   float* __restrict__ dinv,
                                                   int n, int capE, int NB) {
    __shared__ unsigned cntL[NPB];
    __shared__ unsigned ewsL[NPB];
    __shared__ int scanL[MAXNB];
    __shared__ int binbase;
    int b = blockIdx.x;
    int tid = threadIdx.x;
    cntL[tid] = 0; ewsL[tid] = 0;
    // bin base = sum of bin_cnt[0..b)
    scanL[tid] = (tid < b) ? bin_cnt[tid] : 0;
    __syncthreads();
    int m = bin_cnt[b];
    const int2* eb = ebuf + (size_t)b * capE;
    const float* wb = ewb + (size_t)b * capE;
    for (int i = tid; i < m; i += 512) {
        int d = eb[i].y;
        float w = wb[i];
        int ld = d & (NPB - 1);
        atomicAdd(&cntL[ld], 1u);
        atomicAdd(&ewsL[ld], (unsigned)(w * 16777216.0f));   // 2^24 fixed point
    }
    __syncthreads();
    // reduce scanL -> binbase
    #pragma unroll
    for (int off = 256; off > 0; off >>= 1) {
        if (tid < off) scanL[tid] += scanL[tid + off];
        __syncthreads();
    }
    if (tid == 0) binbase = scanL[0];
    __syncthreads();
    // exclusive prefix over cntL (512-wide Hillis-Steele)
    int v = (int)cntL[tid];
    scanL[tid] = v;
    __syncthreads();
    #pragma unroll
    for (int off = 1; off < 512; off <<= 1) {
        int t = (tid >= off) ? scanL[tid - off] : 0;
        __syncthreads();
        scanL[tid] += t;
        __syncthreads();
    }
    int node = b * NPB + tid;
    if (node < n) {
        cnt_g[node] = v;
        rowptr[node] = binbase + scanL[tid] - v;
        dinv[node] = rsqrtf(1.0f + (float)ewsL[tid] * (1.0f / 16777216.0f));
    }
}

// -------------------- pass 3: scatter into CSR (LDS fill counters) --------------------
__global__ __launch_bounds__(512) void k_csr_scatter(const int2* __restrict__ ebuf,
                                                     const float* __restrict__ ewb,
                                                     const int* __restrict__ bin_cnt,
                                                     const int* __restrict__ rowptr,
                                                     const float* __restrict__ dinv,
                                                     unsigned long long* __restrict__ csr,
                                                     int capE) {
    __shared__ unsigned fill[NPB];
    int b = blockIdx.x;
    int tid = threadIdx.x;
    fill[tid] = 0;
    __syncthreads();
    int m = bin_cnt[b];
    const int2* eb = ebuf + (size_t)b * capE;
    const float* wb = ewb + (size_t)b * capE;
    for (int i = tid; i < m; i += 512) {
        int2 sd = eb[i];
        float w = wb[i];
        int ld = sd.y & (NPB - 1);
        int pos = rowptr[sd.y] + (int)atomicAdd(&fill[ld], 1u);
        float norm = dinv[sd.x] * w * dinv[sd.y];
        csr[pos] = (unsigned long long)(unsigned)sd.x |
                   ((unsigned long long)__float_as_uint(norm) << 32);
    }
}

// -------------------- GEMM: out[n,64] = A[n,K] @ W[K,64] --------------------
template<int K, bool SPLITW>
__global__ __launch_bounds__(256) void k_gemm(const float* __restrict__ A,
                                              const float* __restrict__ W0,
                                              const float* __restrict__ W1s,
                                              float* __restrict__ out, int n) {
    __shared__ float Ws[K * 64];
    __shared__ float Xs[64 * K];
    int tid = threadIdx.x;
    int row0 = blockIdx.x * 64;

    constexpr int WF4 = K * 64 / 4;
    for (int j = tid; j < WF4; j += 256) {
        float4 v;
        if (!SPLITW) {
            v = ld4(W0 + j * 4);
        } else {
            int k = (j * 4) >> 6;
            int c = (j * 4) & 63;
            v = (c < 32) ? ld4(W0 + k * 32 + c) : ld4(W1s + k * 32 + (c - 32));
        }
        *(float4*)&Ws[j * 4] = v;
    }
    constexpr int XF4PR = K / 4;
    for (int j = tid; j < 64 * XF4PR; j += 256) {
        int r = j / XF4PR, kc = j % XF4PR;
        int grow = row0 + r;
        float4 v = make_float4(0.f, 0.f, 0.f, 0.f);
        if (grow < n) v = ld4(A + (size_t)grow * K + kc * 4);
        *(float4*)&Xs[r * K + kc * 4] = v;
    }
    __syncthreads();

    int c0 = (tid & 15) * 4;
    int r0 = (tid >> 4) * 4;
    float4 acc[4] = {};
    #pragma unroll 4
    for (int kk = 0; kk < K; kk += 4) {
        float4 w0 = ld4(&Ws[(kk + 0) * 64 + c0]);
        float4 w1 = ld4(&Ws[(kk + 1) * 64 + c0]);
        float4 w2 = ld4(&Ws[(kk + 2) * 64 + c0]);
        float4 w3 = ld4(&Ws[(kk + 3) * 64 + c0]);
        #pragma unroll
        for (int i = 0; i < 4; i++) {
            float4 a = ld4(&Xs[(r0 + i) * K + kk]);
            acc[i].x = fmaf(a.x, w0.x, fmaf(a.y, w1.x, fmaf(a.z, w2.x, fmaf(a.w, w3.x, acc[i].x))));
            acc[i].y = fmaf(a.x, w0.y, fmaf(a.y, w1.y, fmaf(a.z, w2.y, fmaf(a.w, w3.y, acc[i].y))));
            acc[i].z = fmaf(a.x, w0.z, fmaf(a.y, w1.z, fmaf(a.z, w2.z, fmaf(a.w, w3.z, acc[i].z))));
            acc[i].w = fmaf(a.x, w0.w, fmaf(a.y, w1.w, fmaf(a.z, w2.w, fmaf(a.w, w3.w, acc[i].w))));
        }
    }
    #pragma unroll
    for (int i = 0; i < 4; i++) {
        int grow = row0 + r0 + i;
        if (grow < n) *(float4*)&out[(size_t)grow * 64 + c0] = acc[i];
    }
}

// -------------------- propagation (gather over packed CSR), one wave per node --------------------
template<bool RELU, bool SPLIT_OUT>
__global__ __launch_bounds__(256) void k_prop(const float* __restrict__ hin,
                                              const int2* __restrict__ csr,
                                              const int* __restrict__ rowptr,
                                              const int* __restrict__ cnt,
                                              const float* __restrict__ dinv,
                                              const float* __restrict__ bias0,
                                              const float* __restrict__ bias1,
                                              float* __restrict__ out, int n) {
    int node = blockIdx.x * 4 + (threadIdx.x >> 6);
    int c = threadIdx.x & 63;
    if (node >= n) return;
    float di = dinv[node];
    float acc = hin[(size_t)node * 64 + c] * di * di;   // self-loop, weight 1
    const int2* ep = csr + rowptr[node];
    int m = cnt[node];
    int e = 0;
    for (; e + 4 <= m; e += 4) {
        int2 p0 = ep[e], p1 = ep[e + 1], p2 = ep[e + 2], p3 = ep[e + 3];
        acc = fmaf(hin[(size_t)p0.x * 64 + c], __int_as_float(p0.y), acc);
        acc = fmaf(hin[(size_t)p1.x * 64 + c], __int_as_float(p1.y), acc);
        acc = fmaf(hin[(size_t)p2.x * 64 + c], __int_as_float(p2.y), acc);
        acc = fmaf(hin[(size_t)p3.x * 64 + c], __int_as_float(p3.y), acc);
    }
    for (; e < m; e++) {
        int2 p = ep[e];
        acc = fmaf(hin[(size_t)p.x * 64 + c], __int_as_float(p.y), acc);
    }
    if (!SPLIT_OUT) {
        acc += bias0[c];
        if (RELU) acc = fmaxf(acc, 0.0f);
        out[(size_t)node * 64 + c] = acc;
    } else {
        if (c < 32) out[(size_t)node * 32 + c] = acc + bias0[c];
        else        out[(size_t)n * 32 + (size_t)node * 32 + (c - 32)] = acc + bias1[c - 32];
    }
}

// -------------------- launch --------------------
extern "C" void kernel_launch(void* const* d_in, const int* in_sizes, int n_in,
                              void* d_out, int out_size, void* d_ws, size_t ws_size,
                              hipStream_t stream) {
    const float* x   = (const float*)d_in[0];
    const int*   ei  = (const int*)d_in[1];   // [2, E]
    const float* ew  = (const float*)d_in[2];
    const float* W1  = (const float*)d_in[3];
    const float* b1  = (const float*)d_in[4];
    const float* Wmu = (const float*)d_in[5];
    const float* bmu = (const float*)d_in[6];
    const float* Wlv = (const float*)d_in[7];
    const float* blv = (const float*)d_in[8];
    float* outp = (float*)d_out;

    const int n = in_sizes[0] / 128;
    const int E = in_sizes[2];
    const int* src = ei;
    const int* dst = ei + E;
    const int NB = (n + NPB - 1) / NPB;            // 196 bins
    const int capE = E / NB + 2048;                // uniform dst: mean E/NB (+~22 sigma)

    // workspace layout
    size_t o = 0;
    auto alloc = [&](size_t bytes) { void* p = (char*)d_ws + o; o += (bytes + 511) & ~(size_t)511; return p; };
    int*   bin_cnt  = (int*)alloc((size_t)NB * 4);                 // memset 0
    int*   cnt      = (int*)alloc((size_t)n * 4);
    float* dinv     = (float*)alloc((size_t)n * 4);
    int*   rowptr   = (int*)alloc((size_t)n * 4);
    unsigned long long* csr = (unsigned long long*)alloc((size_t)E * 8);
    float* h0  = (float*)alloc((size_t)n * 64 * 4);
    float* h   = (float*)alloc((size_t)n * 64 * 4);
    // binned-edge buffers overlay the h0/h region (dead before GEMM1 runs)
    int2*  ebuf = (int2*)h0;                                       // NB*capE*8 B
    float* ewb  = (float*)((char*)h0 + (size_t)NB * capE * 8);     // NB*capE*4 B (total ~24 MB < 51 MB)
    float* hc  = h0;   // fused mu|lv gemm output (h0 dead after prop1)

    hipMemsetAsync(bin_cnt, 0, (size_t)NB * 4, stream);
    k_bin<<<(E + 4095) / 4096, 1024, NB * 2 * sizeof(int), stream>>>(src, dst, ew, bin_cnt,
                                                                     ebuf, ewb, E, capE, NB);
    k_csr_count<<<NB, 512, 0, stream>>>(ebuf, ewb, bin_cnt, cnt, rowptr, dinv, n, capE, NB);
    k_csr_scatter<<<NB, 512, 0, stream>>>(ebuf, ewb, bin_cnt, rowptr, dinv, csr, capE);

    const int gb = (n + 63) / 64;
    k_gemm<128, false><<<gb, 256, 0, stream>>>(x, W1, nullptr, h0, n);
    k_prop<true, false><<<(n + 3) / 4, 256, 0, stream>>>(h0, (const int2*)csr, rowptr, cnt, dinv,
                                                         b1, nullptr, h, n);
    k_gemm<64, true><<<gb, 256, 0, stream>>>(h, Wmu, Wlv, hc, n);
    k_prop<false, true><<<(n + 3) / 4, 256, 0, stream>>>(hc, (const int2*)csr, rowptr, cnt, dinv,
                                                         bmu, blv, outp, n);
}

// Round 6
// 361.676 us; speedup vs baseline: 1.5385x; 1.0305x over previous
//
#include <hip/hip_runtime.h>

// -------------------- helpers --------------------
static __device__ __forceinline__ float4 ld4(const float* p) { return *(const float4*)p; }
static __device__ __forceinline__ float b2f(unsigned short u) {
    return __uint_as_float((unsigned)u << 16);
}
static __device__ __forceinline__ unsigned short f2b(float f) {   // round-to-nearest-even
    unsigned x = __float_as_uint(f);
    return (unsigned short)((x + 0x7FFFu + ((x >> 16) & 1u)) >> 16);
}

#define NPB 512              // nodes per bin (pow2: ld = d & 511, bin = d >> 9)
#define MAXNB 512            // scan width upper bound for bins

// -------------------- pass 1: partition edges into dst bins --------------------
__global__ __launch_bounds__(1024) void k_bin(const int* __restrict__ src,
                                              const int* __restrict__ dst,
                                              const float* __restrict__ ew,
                                              int* __restrict__ bin_cnt,
                                              int2* __restrict__ ebuf,
                                              float* __restrict__ ewb,
                                              int E, int capE, int NB) {
    extern __shared__ int sh[];          // [NB] hist, then [NB] base
    int* h = sh;
    int* base = sh + NB;
    int tid = threadIdx.x;
    for (int j = tid; j < NB; j += 1024) h[j] = 0;
    __syncthreads();
    int e0 = blockIdx.x * 4096;
    int s[4], b[4], loc[4]; float w[4]; bool act[4];
    #pragma unroll
    for (int i = 0; i < 4; i++) {
        int e = e0 + i * 1024 + tid;
        act[i] = e < E;
        if (act[i]) {
            s[i] = src[e];
            int d = dst[e];
            w[i] = ew[e];
            b[i] = d >> 9;
            loc[i] = atomicAdd(&h[b[i]], 1);
            b[i] |= (d & 511) << 16;   // pack local node id
        }
    }
    __syncthreads();
    for (int j = tid; j < NB; j += 1024) base[j] = atomicAdd(&bin_cnt[j], h[j]);
    __syncthreads();
    #pragma unroll
    for (int i = 0; i < 4; i++) {
        if (act[i]) {
            int bin = b[i] & 0xFFFF;
            int d = (bin << 9) | (b[i] >> 16);
            size_t p = (size_t)bin * capE + base[bin] + loc[i];
            ebuf[p] = make_int2(s[i], d);
            ewb[p] = w[i];
        }
    }
}

// -------------------- pass 2: per-bin count/ewsum (LDS atomics) -> cnt, rowptr, dinv ----------
__global__ __launch_bounds__(512) void k_csr_count(const int2* __restrict__ ebuf,
                                                   const float* __restrict__ ewb,
                                                   const int* __restrict__ bin_cnt,
                                                   int* __restrict__ cnt_g,
                                                   int* __restrict__ rowptr,
                                                   float* __restrict__ dinv,
                                                   int n, int capE, int NB) {
    __shared__ unsigned cntL[NPB];
    __shared__ unsigned ewsL[NPB];
    __shared__ int scanL[MAXNB];
    __shared__ int binbase;
    int b = blockIdx.x;
    int tid = threadIdx.x;
    cntL[tid] = 0; ewsL[tid] = 0;
    scanL[tid] = (tid < b) ? bin_cnt[tid] : 0;
    __syncthreads();
    int m = bin_cnt[b];
    const int2* eb = ebuf + (size_t)b * capE;
    const float* wb = ewb + (size_t)b * capE;
    for (int i = tid; i < m; i += 512) {
        int d = eb[i].y;
        float w = wb[i];
        int ld = d & (NPB - 1);
        atomicAdd(&cntL[ld], 1u);
        atomicAdd(&ewsL[ld], (unsigned)(w * 16777216.0f));   // 2^24 fixed point
    }
    __syncthreads();
    #pragma unroll
    for (int off = 256; off > 0; off >>= 1) {
        if (tid < off) scanL[tid] += scanL[tid + off];
        __syncthreads();
    }
    if (tid == 0) binbase = scanL[0];
    __syncthreads();
    int v = (int)cntL[tid];
    scanL[tid] = v;
    __syncthreads();
    #pragma unroll
    for (int off = 1; off < 512; off <<= 1) {
        int t = (tid >= off) ? scanL[tid - off] : 0;
        __syncthreads();
        scanL[tid] += t;
        __syncthreads();
    }
    int node = b * NPB + tid;
    if (node < n) {
        cnt_g[node] = v;
        rowptr[node] = binbase + scanL[tid] - v;
        dinv[node] = rsqrtf(1.0f + (float)ewsL[tid] * (1.0f / 16777216.0f));
    }
}

// -------------------- pass 3: scatter into CSR (LDS fill counters) --------------------
__global__ __launch_bounds__(512) void k_csr_scatter(const int2* __restrict__ ebuf,
                                                     const float* __restrict__ ewb,
                                                     const int* __restrict__ bin_cnt,
                                                     const int* __restrict__ rowptr,
                                                     const float* __restrict__ dinv,
                                                     unsigned long long* __restrict__ csr,
                                                     int capE) {
    __shared__ unsigned fill[NPB];
    int b = blockIdx.x;
    int tid = threadIdx.x;
    fill[tid] = 0;
    __syncthreads();
    int m = bin_cnt[b];
    const int2* eb = ebuf + (size_t)b * capE;
    const float* wb = ewb + (size_t)b * capE;
    for (int i = tid; i < m; i += 512) {
        int2 sd = eb[i];
        float w = wb[i];
        int ld = sd.y & (NPB - 1);
        int pos = rowptr[sd.y] + (int)atomicAdd(&fill[ld], 1u);
        float norm = dinv[sd.x] * w * dinv[sd.y];
        csr[pos] = (unsigned long long)(unsigned)sd.x |
                   ((unsigned long long)__float_as_uint(norm) << 32);
    }
}

// -------------------- GEMM: out_bf16[n,64] = A[n,K] @ W[K,64] --------------------
// ABF16: A rows are bf16 (ushort). Output always bf16. fp32 accumulate.
template<int K, bool SPLITW, bool ABF16>
__global__ __launch_bounds__(256) void k_gemm(const void* __restrict__ Av,
                                              const float* __restrict__ W0,
                                              const float* __restrict__ W1s,
                                              unsigned short* __restrict__ out, int n) {
    __shared__ float Ws[K * 64];
    __shared__ float Xs[64 * K];
    int tid = threadIdx.x;
    int row0 = blockIdx.x * 64;

    constexpr int WF4 = K * 64 / 4;
    for (int j = tid; j < WF4; j += 256) {
        float4 v;
        if (!SPLITW) {
            v = ld4(W0 + j * 4);
        } else {
            int k = (j * 4) >> 6;
            int c = (j * 4) & 63;
            v = (c < 32) ? ld4(W0 + k * 32 + c) : ld4(W1s + k * 32 + (c - 32));
        }
        *(float4*)&Ws[j * 4] = v;
    }
    constexpr int XF4PR = K / 4;
    for (int j = tid; j < 64 * XF4PR; j += 256) {
        int r = j / XF4PR, kc = j % XF4PR;
        int grow = row0 + r;
        float4 v = make_float4(0.f, 0.f, 0.f, 0.f);
        if (grow < n) {
            if (ABF16) {
                const unsigned short* Ab = (const unsigned short*)Av;
                ushort4 u = *(const ushort4*)(Ab + (size_t)grow * K + kc * 4);
                v = make_float4(b2f(u.x), b2f(u.y), b2f(u.z), b2f(u.w));
            } else {
                v = ld4((const float*)Av + (size_t)grow * K + kc * 4);
            }
        }
        *(float4*)&Xs[r * K + kc * 4] = v;
    }
    __syncthreads();

    int c0 = (tid & 15) * 4;
    int r0 = (tid >> 4) * 4;
    float4 acc[4] = {};
    #pragma unroll 4
    for (int kk = 0; kk < K; kk += 4) {
        float4 w0 = ld4(&Ws[(kk + 0) * 64 + c0]);
        float4 w1 = ld4(&Ws[(kk + 1) * 64 + c0]);
        float4 w2 = ld4(&Ws[(kk + 2) * 64 + c0]);
        float4 w3 = ld4(&Ws[(kk + 3) * 64 + c0]);
        #pragma unroll
        for (int i = 0; i < 4; i++) {
            float4 a = ld4(&Xs[(r0 + i) * K + kk]);
            acc[i].x = fmaf(a.x, w0.x, fmaf(a.y, w1.x, fmaf(a.z, w2.x, fmaf(a.w, w3.x, acc[i].x))));
            acc[i].y = fmaf(a.x, w0.y, fmaf(a.y, w1.y, fmaf(a.z, w2.y, fmaf(a.w, w3.y, acc[i].y))));
            acc[i].z = fmaf(a.x, w0.z, fmaf(a.y, w1.z, fmaf(a.z, w2.z, fmaf(a.w, w3.z, acc[i].z))));
            acc[i].w = fmaf(a.x, w0.w, fmaf(a.y, w1.w, fmaf(a.z, w2.w, fmaf(a.w, w3.w, acc[i].w))));
        }
    }
    #pragma unroll
    for (int i = 0; i < 4; i++) {
        int grow = row0 + r0 + i;
        if (grow < n) {
            ushort4 u = make_ushort4(f2b(acc[i].x), f2b(acc[i].y), f2b(acc[i].z), f2b(acc[i].w));
            *(ushort4*)&out[(size_t)grow * 64 + c0] = u;
        }
    }
}

// -------------------- propagation (gather over packed CSR), one wave per node ------------
// hin: bf16 [n,64]. SPLIT_OUT: write fp32 [n,32]+[n,32] (mu|lv); else write bf16 [n,64] +ReLU.
template<bool RELU, bool SPLIT_OUT>
__global__ __launch_bounds__(256) void k_prop(const unsigned short* __restrict__ hin,
                                              const int2* __restrict__ csr,
                                              const int* __restrict__ rowptr,
                                              const int* __restrict__ cnt,
                                              const float* __restrict__ dinv,
                                              const float* __restrict__ bias0,
                                              const float* __restrict__ bias1,
                                              void* __restrict__ outv, int n) {
    int node = blockIdx.x * 4 + (threadIdx.x >> 6);
    int c = threadIdx.x & 63;
    if (node >= n) return;
    float di = dinv[node];
    float acc = b2f(hin[(size_t)node * 64 + c]) * di * di;   // self-loop, weight 1
    const int2* ep = csr + rowptr[node];
    int m = cnt[node];
    int e = 0;
    for (; e + 4 <= m; e += 4) {
        int2 p0 = ep[e], p1 = ep[e + 1], p2 = ep[e + 2], p3 = ep[e + 3];
        acc = fmaf(b2f(hin[(size_t)p0.x * 64 + c]), __int_as_float(p0.y), acc);
        acc = fmaf(b2f(hin[(size_t)p1.x * 64 + c]), __int_as_float(p1.y), acc);
        acc = fmaf(b2f(hin[(size_t)p2.x * 64 + c]), __int_as_float(p2.y), acc);
        acc = fmaf(b2f(hin[(size_t)p3.x * 64 + c]), __int_as_float(p3.y), acc);
    }
    for (; e < m; e++) {
        int2 p = ep[e];
        acc = fmaf(b2f(hin[(size_t)p.x * 64 + c]), __int_as_float(p.y), acc);
    }
    if (!SPLIT_OUT) {
        acc += bias0[c];
        if (RELU) acc = fmaxf(acc, 0.0f);
        ((unsigned short*)outv)[(size_t)node * 64 + c] = f2b(acc);
    } else {
        float* out = (float*)outv;
        if (c < 32) out[(size_t)node * 32 + c] = acc + bias0[c];
        else        out[(size_t)n * 32 + (size_t)node * 32 + (c - 32)] = acc + bias1[c - 32];
    }
}

// -------------------- launch --------------------
extern "C" void kernel_launch(void* const* d_in, const int* in_sizes, int n_in,
                              void* d_out, int out_size, void* d_ws, size_t ws_size,
                              hipStream_t stream) {
    const float* x   = (const float*)d_in[0];
    const int*   ei  = (const int*)d_in[1];   // [2, E]
    const float* ew  = (const float*)d_in[2];
    const float* W1  = (const float*)d_in[3];
    const float* b1  = (const float*)d_in[4];
    const float* Wmu = (const float*)d_in[5];
    const float* bmu = (const float*)d_in[6];
    const float* Wlv = (const float*)d_in[7];
    const float* blv = (const float*)d_in[8];
    float* outp = (float*)d_out;

    const int n = in_sizes[0] / 128;
    const int E = in_sizes[2];
    const int* src = ei;
    const int* dst = ei + E;
    const int NB = (n + NPB - 1) / NPB;            // bins of 512 nodes
    const int capE = E / NB + 2048;                // uniform dst: mean E/NB + slack

    // workspace layout (no overlays; ~64 MB total)
    size_t o = 0;
    auto alloc = [&](size_t bytes) { void* p = (char*)d_ws + o; o += (bytes + 511) & ~(size_t)511; return p; };
    int*   bin_cnt  = (int*)alloc((size_t)NB * 4);                 // memset 0
    int*   cnt      = (int*)alloc((size_t)n * 4);
    float* dinv     = (float*)alloc((size_t)n * 4);
    int*   rowptr   = (int*)alloc((size_t)n * 4);
    unsigned long long* csr = (unsigned long long*)alloc((size_t)E * 8);
    int2*  ebuf     = (int2*)alloc((size_t)NB * capE * 8);
    float* ewb      = (float*)alloc((size_t)NB * capE * 4);
    unsigned short* h0 = (unsigned short*)alloc((size_t)n * 64 * 2);   // bf16
    unsigned short* h  = (unsigned short*)alloc((size_t)n * 64 * 2);   // bf16
    unsigned short* hc = h0;   // gemm2 output reuses h0 (dead after prop1)

    hipMemsetAsync(bin_cnt, 0, (size_t)NB * 4, stream);
    k_bin<<<(E + 4095) / 4096, 1024, NB * 2 * sizeof(int), stream>>>(src, dst, ew, bin_cnt,
                                                                     ebuf, ewb, E, capE, NB);
    k_csr_count<<<NB, 512, 0, stream>>>(ebuf, ewb, bin_cnt, cnt, rowptr, dinv, n, capE, NB);
    k_csr_scatter<<<NB, 512, 0, stream>>>(ebuf, ewb, bin_cnt, rowptr, dinv, csr, capE);

    const int gb = (n + 63) / 64;
    k_gemm<128, false, false><<<gb, 256, 0, stream>>>(x, W1, nullptr, h0, n);
    k_prop<true, false><<<(n + 3) / 4, 256, 0, stream>>>(h0, (const int2*)csr, rowptr, cnt, dinv,
                                                         b1, nullptr, h, n);
    k_gemm<64, true, true><<<gb, 256, 0, stream>>>(h, Wmu, Wlv, hc, n);
    k_prop<false, true><<<(n + 3) / 4, 256, 0, stream>>>(hc, (const int2*)csr, rowptr, cnt, dinv,
                                                         bmu, blv, outp, n);
}

// Round 7
// 359.847 us; speedup vs baseline: 1.5463x; 1.0051x over previous
//
#include <hip/hip_runtime.h>

// -------------------- helpers --------------------
static __device__ __forceinline__ float4 ld4(const float* p) { return *(const float4*)p; }
static __device__ __forceinline__ float b2f(unsigned short u) {
    return __uint_as_float((unsigned)u << 16);
}
static __device__ __forceinline__ float b2f_lo(unsigned u) { return __uint_as_float(u << 16); }
static __device__ __forceinline__ float b2f_hi(unsigned u) { return __uint_as_float(u & 0xFFFF0000u); }
static __device__ __forceinline__ unsigned short f2b(float f) {   // round-to-nearest-even
    unsigned x = __float_as_uint(f);
    return (unsigned short)((x + 0x7FFFu + ((x >> 16) & 1u)) >> 16);
}

#define NPB 512              // nodes per bin (pow2: ld = d & 511, bin = d >> 9)
#define MAXNB 512            // scan width upper bound for bins

// -------------------- pass 1: partition edges into dst bins --------------------
__global__ __launch_bounds__(1024) void k_bin(const int* __restrict__ src,
                                              const int* __restrict__ dst,
                                              const float* __restrict__ ew,
                                              int* __restrict__ bin_cnt,
                                              int2* __restrict__ ebuf,
                                              float* __restrict__ ewb,
                                              int E, int capE, int NB) {
    extern __shared__ int sh[];          // [NB] hist, then [NB] base
    int* h = sh;
    int* base = sh + NB;
    int tid = threadIdx.x;
    for (int j = tid; j < NB; j += 1024) h[j] = 0;
    __syncthreads();
    int e0 = blockIdx.x * 4096;
    int s[4], b[4], loc[4]; float w[4]; bool act[4];
    #pragma unroll
    for (int i = 0; i < 4; i++) {
        int e = e0 + i * 1024 + tid;
        act[i] = e < E;
        if (act[i]) {
            s[i] = src[e];
            int d = dst[e];
            w[i] = ew[e];
            b[i] = d >> 9;
            loc[i] = atomicAdd(&h[b[i]], 1);
            b[i] |= (d & 511) << 16;   // pack local node id
        }
    }
    __syncthreads();
    for (int j = tid; j < NB; j += 1024) base[j] = atomicAdd(&bin_cnt[j], h[j]);
    __syncthreads();
    #pragma unroll
    for (int i = 0; i < 4; i++) {
        if (act[i]) {
            int bin = b[i] & 0xFFFF;
            int d = (bin << 9) | (b[i] >> 16);
            size_t p = (size_t)bin * capE + base[bin] + loc[i];
            ebuf[p] = make_int2(s[i], d);
            ewb[p] = w[i];
        }
    }
}

// -------------------- pass 2: per-bin count/ewsum (LDS atomics) -> cnt, rowptr, dinv ----------
__global__ __launch_bounds__(512) void k_csr_count(const int2* __restrict__ ebuf,
                                                   const float* __restrict__ ewb,
                                                   const int* __restrict__ bin_cnt,
                                                   int* __restrict__ cnt_g,
                                                   int* __restrict__ rowptr,
                                                   float* __restrict__ dinv,
                                                   int n, int capE, int NB) {
    __shared__ unsigned cntL[NPB];
    __shared__ unsigned ewsL[NPB];
    __shared__ int scanL[MAXNB];
    __shared__ int binbase;
    int b = blockIdx.x;
    int tid = threadIdx.x;
    cntL[tid] = 0; ewsL[tid] = 0;
    scanL[tid] = (tid < b) ? bin_cnt[tid] : 0;
    __syncthreads();
    int m = bin_cnt[b];
    const int2* eb = ebuf + (size_t)b * capE;
    const float* wb = ewb + (size_t)b * capE;
    for (int i = tid; i < m; i += 512) {
        int d = eb[i].y;
        float w = wb[i];
        int ld = d & (NPB - 1);
        atomicAdd(&cntL[ld], 1u);
        atomicAdd(&ewsL[ld], (unsigned)(w * 16777216.0f));   // 2^24 fixed point
    }
    __syncthreads();
    #pragma unroll
    for (int off = 256; off > 0; off >>= 1) {
        if (tid < off) scanL[tid] += scanL[tid + off];
        __syncthreads();
    }
    if (tid == 0) binbase = scanL[0];
    __syncthreads();
    int v = (int)cntL[tid];
    scanL[tid] = v;
    __syncthreads();
    #pragma unroll
    for (int off = 1; off < 512; off <<= 1) {
        int t = (tid >= off) ? scanL[tid - off] : 0;
        __syncthreads();
        scanL[tid] += t;
        __syncthreads();
    }
    int node = b * NPB + tid;
    if (node < n) {
        cnt_g[node] = v;
        rowptr[node] = binbase + scanL[tid] - v;
        dinv[node] = rsqrtf(1.0f + (float)ewsL[tid] * (1.0f / 16777216.0f));
    }
}

// -------------------- pass 3: scatter into CSR (LDS fill counters) --------------------
__global__ __launch_bounds__(512) void k_csr_scatter(const int2* __restrict__ ebuf,
                                                     const float* __restrict__ ewb,
                                                     const int* __restrict__ bin_cnt,
                                                     const int* __restrict__ rowptr,
                                                     const float* __restrict__ dinv,
                                                     unsigned long long* __restrict__ csr,
                                                     int capE) {
    __shared__ unsigned fill[NPB];
    int b = blockIdx.x;
    int tid = threadIdx.x;
    fill[tid] = 0;
    __syncthreads();
    int m = bin_cnt[b];
    const int2* eb = ebuf + (size_t)b * capE;
    const float* wb = ewb + (size_t)b * capE;
    for (int i = tid; i < m; i += 512) {
        int2 sd = eb[i];
        float w = wb[i];
        int ld = sd.y & (NPB - 1);
        int pos = rowptr[sd.y] + (int)atomicAdd(&fill[ld], 1u);
        float norm = dinv[sd.x] * w * dinv[sd.y];
        csr[pos] = (unsigned long long)(unsigned)sd.x |
                   ((unsigned long long)__float_as_uint(norm) << 32);
    }
}

// -------------------- GEMM: out_bf16[n,64] = A[n,K] @ W[K,64] --------------------
template<int K, bool SPLITW, bool ABF16>
__global__ __launch_bounds__(256) void k_gemm(const void* __restrict__ Av,
                                              const float* __restrict__ W0,
                                              const float* __restrict__ W1s,
                                              unsigned short* __restrict__ out, int n) {
    __shared__ float Ws[K * 64];
    __shared__ float Xs[64 * K];
    int tid = threadIdx.x;
    int row0 = blockIdx.x * 64;

    constexpr int WF4 = K * 64 / 4;
    for (int j = tid; j < WF4; j += 256) {
        float4 v;
        if (!SPLITW) {
            v = ld4(W0 + j * 4);
        } else {
            int k = (j * 4) >> 6;
            int c = (j * 4) & 63;
            v = (c < 32) ? ld4(W0 + k * 32 + c) : ld4(W1s + k * 32 + (c - 32));
        }
        *(float4*)&Ws[j * 4] = v;
    }
    constexpr int XF4PR = K / 4;
    for (int j = tid; j < 64 * XF4PR; j += 256) {
        int r = j / XF4PR, kc = j % XF4PR;
        int grow = row0 + r;
        float4 v = make_float4(0.f, 0.f, 0.f, 0.f);
        if (grow < n) {
            if (ABF16) {
                const unsigned short* Ab = (const unsigned short*)Av;
                ushort4 u = *(const ushort4*)(Ab + (size_t)grow * K + kc * 4);
                v = make_float4(b2f(u.x), b2f(u.y), b2f(u.z), b2f(u.w));
            } else {
                v = ld4((const float*)Av + (size_t)grow * K + kc * 4);
            }
        }
        *(float4*)&Xs[r * K + kc * 4] = v;
    }
    __syncthreads();

    int c0 = (tid & 15) * 4;
    int r0 = (tid >> 4) * 4;
    float4 acc[4] = {};
    #pragma unroll 4
    for (int kk = 0; kk < K; kk += 4) {
        float4 w0 = ld4(&Ws[(kk + 0) * 64 + c0]);
        float4 w1 = ld4(&Ws[(kk + 1) * 64 + c0]);
        float4 w2 = ld4(&Ws[(kk + 2) * 64 + c0]);
        float4 w3 = ld4(&Ws[(kk + 3) * 64 + c0]);
        #pragma unroll
        for (int i = 0; i < 4; i++) {
            float4 a = ld4(&Xs[(r0 + i) * K + kk]);
            acc[i].x = fmaf(a.x, w0.x, fmaf(a.y, w1.x, fmaf(a.z, w2.x, fmaf(a.w, w3.x, acc[i].x))));
            acc[i].y = fmaf(a.x, w0.y, fmaf(a.y, w1.y, fmaf(a.z, w2.y, fmaf(a.w, w3.y, acc[i].y))));
            acc[i].z = fmaf(a.x, w0.z, fmaf(a.y, w1.z, fmaf(a.z, w2.z, fmaf(a.w, w3.z, acc[i].z))));
            acc[i].w = fmaf(a.x, w0.w, fmaf(a.y, w1.w, fmaf(a.z, w2.w, fmaf(a.w, w3.w, acc[i].w))));
        }
    }
    #pragma unroll
    for (int i = 0; i < 4; i++) {
        int grow = row0 + r0 + i;
        if (grow < n) {
            ushort4 u = make_ushort4(f2b(acc[i].x), f2b(acc[i].y), f2b(acc[i].z), f2b(acc[i].w));
            *(ushort4*)&out[(size_t)grow * 64 + c0] = u;
        }
    }
}

// -------------------- propagation: one wave per node, 4 edges per VMEM instruction ----------
// Wave split in 4 quarters (q = lane>>4, t = lane&15). Quarter q gathers edge e+q's row with
// uint2 (16 lanes x 8 B = 128 B row). Lane accumulates channels 4t..4t+3 over edges == q mod 4.
// Epilogue: shfl_xor(16,32) sums quarters; quarter 0 adds self-loop + bias and writes the row.
template<bool RELU, bool SPLIT_OUT>
__global__ __launch_bounds__(256) void k_prop(const unsigned short* __restrict__ hin,
                                              const int2* __restrict__ csr,
                                              const int* __restrict__ rowptr,
                                              const int* __restrict__ cnt,
                                              const float* __restrict__ dinv,
                                              const float* __restrict__ bias0,
                                              const float* __restrict__ bias1,
                                              void* __restrict__ outv, int n) {
    int node = blockIdx.x * 4 + (threadIdx.x >> 6);
    if (node >= n) return;
    int lane = threadIdx.x & 63;
    int q = lane >> 4;          // quarter: edge slot
    int t = lane & 15;          // sub-lane: channel quad 4t..4t+3
    float a0 = 0.f, a1 = 0.f, a2 = 0.f, a3 = 0.f;
    const int2* ep = csr + rowptr[node];
    int m = cnt[node];
    for (int e = 0; e < m; e += 8) {
        int e1 = e + q, e2 = e + 4 + q;
        if (e1 < m) {
            int2 p = ep[e1];
            uint2 r = *(const uint2*)(hin + (size_t)p.x * 64 + t * 4);
            float nm = __int_as_float(p.y);
            a0 = fmaf(b2f_lo(r.x), nm, a0);
            a1 = fmaf(b2f_hi(r.x), nm, a1);
            a2 = fmaf(b2f_lo(r.y), nm, a2);
            a3 = fmaf(b2f_hi(r.y), nm, a3);
        }
        if (e2 < m) {
            int2 p = ep[e2];
            uint2 r = *(const uint2*)(hin + (size_t)p.x * 64 + t * 4);
            float nm = __int_as_float(p.y);
            a0 = fmaf(b2f_lo(r.x), nm, a0);
            a1 = fmaf(b2f_hi(r.x), nm, a1);
            a2 = fmaf(b2f_lo(r.y), nm, a2);
            a3 = fmaf(b2f_hi(r.y), nm, a3);
        }
    }
    // sum the 4 quarters
    a0 += __shfl_xor(a0, 16); a0 += __shfl_xor(a0, 32);
    a1 += __shfl_xor(a1, 16); a1 += __shfl_xor(a1, 32);
    a2 += __shfl_xor(a2, 16); a2 += __shfl_xor(a2, 32);
    a3 += __shfl_xor(a3, 16); a3 += __shfl_xor(a3, 32);
    if (q != 0) return;
    // self-loop + bias + store (channels 4t..4t+3)
    float di = dinv[node];
    float sw = di * di;
    uint2 sr = *(const uint2*)(hin + (size_t)node * 64 + t * 4);
    a0 = fmaf(b2f_lo(sr.x), sw, a0);
    a1 = fmaf(b2f_hi(sr.x), sw, a1);
    a2 = fmaf(b2f_lo(sr.y), sw, a2);
    a3 = fmaf(b2f_hi(sr.y), sw, a3);
    if (!SPLIT_OUT) {
        float4 bb = ld4(bias0 + t * 4);
        a0 += bb.x; a1 += bb.y; a2 += bb.z; a3 += bb.w;
        if (RELU) {
            a0 = fmaxf(a0, 0.f); a1 = fmaxf(a1, 0.f);
            a2 = fmaxf(a2, 0.f); a3 = fmaxf(a3, 0.f);
        }
        ushort4 u = make_ushort4(f2b(a0), f2b(a1), f2b(a2), f2b(a3));
        *(ushort4*)((unsigned short*)outv + (size_t)node * 64 + t * 4) = u;
    } else {
        float* out = (float*)outv;
        if (t < 8) {
            float4 bb = ld4(bias0 + t * 4);
            float4 v = make_float4(a0 + bb.x, a1 + bb.y, a2 + bb.z, a3 + bb.w);
            *(float4*)&out[(size_t)node * 32 + t * 4] = v;
        } else {
            float4 bb = ld4(bias1 + (t - 8) * 4);
            float4 v = make_float4(a0 + bb.x, a1 + bb.y, a2 + bb.z, a3 + bb.w);
            *(float4*)&out[(size_t)n * 32 + (size_t)node * 32 + (t - 8) * 4] = v;
        }
    }
}

// -------------------- launch --------------------
extern "C" void kernel_launch(void* const* d_in, const int* in_sizes, int n_in,
                              void* d_out, int out_size, void* d_ws, size_t ws_size,
                              hipStream_t stream) {
    const float* x   = (const float*)d_in[0];
    const int*   ei  = (const int*)d_in[1];   // [2, E]
    const float* ew  = (const float*)d_in[2];
    const float* W1  = (const float*)d_in[3];
    const float* b1  = (const float*)d_in[4];
    const float* Wmu = (const float*)d_in[5];
    const float* bmu = (const float*)d_in[6];
    const float* Wlv = (const float*)d_in[7];
    const float* blv = (const float*)d_in[8];
    float* outp = (float*)d_out;

    const int n = in_sizes[0] / 128;
    const int E = in_sizes[2];
    const int* src = ei;
    const int* dst = ei + E;
    const int NB = (n + NPB - 1) / NPB;            // bins of 512 nodes
    const int capE = E / NB + 2048;                // uniform dst: mean E/NB + slack

    // workspace layout
    size_t o = 0;
    auto alloc = [&](size_t bytes) { void* p = (char*)d_ws + o; o += (bytes + 511) & ~(size_t)511; return p; };
    int*   bin_cnt  = (int*)alloc((size_t)NB * 4);                 // memset 0
    int*   cnt      = (int*)alloc((size_t)n * 4);
    float* dinv     = (float*)alloc((size_t)n * 4);
    int*   rowptr   = (int*)alloc((size_t)n * 4);
    unsigned long long* csr = (unsigned long long*)alloc((size_t)E * 8);
    int2*  ebuf     = (int2*)alloc((size_t)NB * capE * 8);
    float* ewb      = (float*)alloc((size_t)NB * capE * 4);
    unsigned short* h0 = (unsigned short*)alloc((size_t)n * 64 * 2);   // bf16
    unsigned short* h  = (unsigned short*)alloc((size_t)n * 64 * 2);   // bf16
    unsigned short* hc = h0;   // gemm2 output reuses h0 (dead after prop1)

    hipMemsetAsync(bin_cnt, 0, (size_t)NB * 4, stream);
    k_bin<<<(E + 4095) / 4096, 1024, NB * 2 * sizeof(int), stream>>>(src, dst, ew, bin_cnt,
                                                                     ebuf, ewb, E, capE, NB);
    k_csr_count<<<NB, 512, 0, stream>>>(ebuf, ewb, bin_cnt, cnt, rowptr, dinv, n, capE, NB);
    k_csr_scatter<<<NB, 512, 0, stream>>>(ebuf, ewb, bin_cnt, rowptr, dinv, csr, capE);

    const int gb = (n + 63) / 64;
    k_gemm<128, false, false><<<gb, 256, 0, stream>>>(x, W1, nullptr, h0, n);
    k_prop<true, false><<<(n + 3) / 4, 256, 0, stream>>>(h0, (const int2*)csr, rowptr, cnt, dinv,
                                                         b1, nullptr, h, n);
    k_gemm<64, true, true><<<gb, 256, 0, stream>>>(h, Wmu, Wlv, hc, n);
    k_prop<false, true><<<(n + 3) / 4, 256, 0, stream>>>(hc, (const int2*)csr, rowptr, cnt, dinv,
                                                         bmu, blv, outp, n);
}

// Round 8
// 338.300 us; speedup vs baseline: 1.6448x; 1.0637x over previous
//
#include <hip/hip_runtime.h>

// -------------------- helpers --------------------
static __device__ __forceinline__ float4 ld4(const float* p) { return *(const float4*)p; }
static __device__ __forceinline__ float b2f(unsigned short u) {
    return __uint_as_float((unsigned)u << 16);
}
static __device__ __forceinline__ float b2f_lo(unsigned u) { return __uint_as_float(u << 16); }
static __device__ __forceinline__ float b2f_hi(unsigned u) { return __uint_as_float(u & 0xFFFF0000u); }
static __device__ __forceinline__ unsigned short f2b(float f) {   // round-to-nearest-even
    unsigned x = __float_as_uint(f);
    return (unsigned short)((x + 0x7FFFu + ((x >> 16) & 1u)) >> 16);
}

#define NPB 512              // nodes per bin (pow2: ld = d & 511, bin = d >> 9)

// math refactor: out[d] = dinv[d]*( g[d] + sum_e w_e * g[src_e] ) + bias,  g = dinv (.) h
// -> CSR stores (src, raw ew); dinv folded into gemm epilogue (g) and prop epilogue.

// -------------------- pass 1: partition edges into dst bins (packed u64) --------------------
// entry: [ew:32][ld:9][src:17]  (n < 2^17)
__global__ __launch_bounds__(1024) void k_bin(const int* __restrict__ src,
                                              const int* __restrict__ dst,
                                              const float* __restrict__ ew,
                                              int* __restrict__ bin_cnt,
                                              unsigned long long* __restrict__ ebuf,
                                              int E, int capE, int NB) {
    extern __shared__ int sh[];          // [NB] hist, then [NB] base
    int* h = sh;
    int* base = sh + NB;
    int tid = threadIdx.x;
    for (int j = tid; j < NB; j += 1024) h[j] = 0;
    __syncthreads();
    int e0 = blockIdx.x * 4096;
    unsigned long long pk[4]; int b[4], loc[4]; bool act[4];
    #pragma unroll
    for (int i = 0; i < 4; i++) {
        int e = e0 + i * 1024 + tid;
        act[i] = e < E;
        if (act[i]) {
            int s = src[e];
            int d = dst[e];
            float w = ew[e];
            b[i] = d >> 9;
            pk[i] = ((unsigned long long)__float_as_uint(w) << 32) |
                    (unsigned)((d & (NPB - 1)) << 17) | (unsigned)s;
            loc[i] = atomicAdd(&h[b[i]], 1);
        }
    }
    __syncthreads();
    for (int j = tid; j < NB; j += 1024) base[j] = atomicAdd(&bin_cnt[j], h[j]);
    __syncthreads();
    #pragma unroll
    for (int i = 0; i < 4; i++) {
        if (act[i]) ebuf[(size_t)b[i] * capE + base[b[i]] + loc[i]] = pk[i];
    }
}

// -------------------- pass 2: per-bin count+scan+scatter (all LDS), one block per bin ----------
__global__ __launch_bounds__(512) void k_csr_build(const unsigned long long* __restrict__ ebuf,
                                                   const int* __restrict__ bin_cnt,
                                                   int2* __restrict__ rowcnt,
                                                   float* __restrict__ dinv,
                                                   unsigned long long* __restrict__ csr,
                                                   int n, int capE) {
    __shared__ unsigned cntL[NPB];
    __shared__ unsigned ewsL[NPB];
    __shared__ int scanL[NPB];
    __shared__ int rowL[NPB];
    __shared__ unsigned fillL[NPB];
    __shared__ int binbase_s;
    int b = blockIdx.x;
    int tid = threadIdx.x;
    cntL[tid] = 0; ewsL[tid] = 0; fillL[tid] = 0;
    scanL[tid] = (tid < b) ? bin_cnt[tid] : 0;
    __syncthreads();
    int m = bin_cnt[b];
    const unsigned long long* eb = ebuf + (size_t)b * capE;
    for (int i = tid; i < m; i += 512) {
        unsigned long long pk = eb[i];
        int ld = (int)((pk >> 17) & (NPB - 1));
        float w = __uint_as_float((unsigned)(pk >> 32));
        atomicAdd(&cntL[ld], 1u);
        atomicAdd(&ewsL[ld], (unsigned)(w * 16777216.0f));   // 2^24 fixed point
    }
    __syncthreads();
    // bin base = sum over bins < b
    #pragma unroll
    for (int off = 256; off > 0; off >>= 1) {
        if (tid < off) scanL[tid] += scanL[tid + off];
        __syncthreads();
    }
    if (tid == 0) binbase_s = scanL[0];
    __syncthreads();
    // exclusive prefix over cntL
    int v = (int)cntL[tid];
    scanL[tid] = v;
    __syncthreads();
    #pragma unroll
    for (int off = 1; off < 512; off <<= 1) {
        int t = (tid >= off) ? scanL[tid - off] : 0;
        __syncthreads();
        scanL[tid] += t;
        __syncthreads();
    }
    int rp = binbase_s + scanL[tid] - v;
    rowL[tid] = rp;
    int node = b * NPB + tid;
    if (node < n) {
        rowcnt[node] = make_int2(rp, v);
        dinv[node] = rsqrtf(1.0f + (float)ewsL[tid] * (1.0f / 16777216.0f));
    }
    __syncthreads();
    // scatter (edges L2-warm from first pass); csr entry = (src, raw ew)
    for (int i = tid; i < m; i += 512) {
        unsigned long long pk = eb[i];
        int s = (int)(pk & 0x1FFFF);
        int ld = (int)((pk >> 17) & (NPB - 1));
        int pos = rowL[ld] + (int)atomicAdd(&fillL[ld], 1u);
        csr[pos] = (unsigned long long)(unsigned)s | (pk & 0xFFFFFFFF00000000ull);
    }
}

// -------------------- GEMM: g_bf16[n,64] = dinv (.) (A[n,K] @ W[K,64]) --------------------
template<int K, bool SPLITW, bool ABF16>
__global__ __launch_bounds__(256) void k_gemm(const void* __restrict__ Av,
                                              const float* __restrict__ W0,
                                              const float* __restrict__ W1s,
                                              const float* __restrict__ dinv,
                                              unsigned short* __restrict__ out, int n) {
    __shared__ float Ws[K * 64];
    __shared__ float Xs[64 * K];
    int tid = threadIdx.x;
    int row0 = blockIdx.x * 64;

    constexpr int WF4 = K * 64 / 4;
    for (int j = tid; j < WF4; j += 256) {
        float4 v;
        if (!SPLITW) {
            v = ld4(W0 + j * 4);
        } else {
            int k = (j * 4) >> 6;
            int c = (j * 4) & 63;
            v = (c < 32) ? ld4(W0 + k * 32 + c) : ld4(W1s + k * 32 + (c - 32));
        }
        *(float4*)&Ws[j * 4] = v;
    }
    constexpr int XF4PR = K / 4;
    for (int j = tid; j < 64 * XF4PR; j += 256) {
        int r = j / XF4PR, kc = j % XF4PR;
        int grow = row0 + r;
        float4 v = make_float4(0.f, 0.f, 0.f, 0.f);
        if (grow < n) {
            if (ABF16) {
                const unsigned short* Ab = (const unsigned short*)Av;
                ushort4 u = *(const ushort4*)(Ab + (size_t)grow * K + kc * 4);
                v = make_float4(b2f(u.x), b2f(u.y), b2f(u.z), b2f(u.w));
            } else {
                v = ld4((const float*)Av + (size_t)grow * K + kc * 4);
            }
        }
        *(float4*)&Xs[r * K + kc * 4] = v;
    }
    __syncthreads();

    int c0 = (tid & 15) * 4;
    int r0 = (tid >> 4) * 4;
    float4 acc[4] = {};
    #pragma unroll 4
    for (int kk = 0; kk < K; kk += 4) {
        float4 w0 = ld4(&Ws[(kk + 0) * 64 + c0]);
        float4 w1 = ld4(&Ws[(kk + 1) * 64 + c0]);
        float4 w2 = ld4(&Ws[(kk + 2) * 64 + c0]);
        float4 w3 = ld4(&Ws[(kk + 3) * 64 + c0]);
        #pragma unroll
        for (int i = 0; i < 4; i++) {
            float4 a = ld4(&Xs[(r0 + i) * K + kk]);
            acc[i].x = fmaf(a.x, w0.x, fmaf(a.y, w1.x, fmaf(a.z, w2.x, fmaf(a.w, w3.x, acc[i].x))));
            acc[i].y = fmaf(a.x, w0.y, fmaf(a.y, w1.y, fmaf(a.z, w2.y, fmaf(a.w, w3.y, acc[i].y))));
            acc[i].z = fmaf(a.x, w0.z, fmaf(a.y, w1.z, fmaf(a.z, w2.z, fmaf(a.w, w3.z, acc[i].z))));
            acc[i].w = fmaf(a.x, w0.w, fmaf(a.y, w1.w, fmaf(a.z, w2.w, fmaf(a.w, w3.w, acc[i].w))));
        }
    }
    #pragma unroll
    for (int i = 0; i < 4; i++) {
        int grow = row0 + r0 + i;
        if (grow < n) {
            float sc = dinv[grow];
            ushort4 u = make_ushort4(f2b(acc[i].x * sc), f2b(acc[i].y * sc),
                                     f2b(acc[i].z * sc), f2b(acc[i].w * sc));
            *(ushort4*)&out[(size_t)grow * 64 + c0] = u;
        }
    }
}

// -------------------- propagation: one wave per node, 4 edges per VMEM instruction ----------
// g is dinv-scaled; csr = (src, raw ew). out = dinv[d]*(g[d] + sum w*g[s]) + bias.
template<bool RELU, bool SPLIT_OUT>
__global__ __launch_bounds__(256) void k_prop(const unsigned short* __restrict__ g,
                                              const int2* __restrict__ csr,
                                              const int2* __restrict__ rowcnt,
                                              const float* __restrict__ dinv,
                                              const float* __restrict__ bias0,
                                              const float* __restrict__ bias1,
                                              void* __restrict__ outv, int n) {
    int node = blockIdx.x * 4 + (threadIdx.x >> 6);
    if (node >= n) return;
    int lane = threadIdx.x & 63;
    int q = lane >> 4;          // quarter: edge slot
    int t = lane & 15;          // sub-lane: channel quad 4t..4t+3
    float a0 = 0.f, a1 = 0.f, a2 = 0.f, a3 = 0.f;
    int2 rc = rowcnt[node];
    const int2* ep = csr + rc.x;
    int m = rc.y;
    for (int e = 0; e < m; e += 8) {
        int e1 = e + q, e2 = e + 4 + q;
        if (e1 < m) {
            int2 p = ep[e1];
            uint2 r = *(const uint2*)(g + (size_t)p.x * 64 + t * 4);
            float nm = __int_as_float(p.y);
            a0 = fmaf(b2f_lo(r.x), nm, a0);
            a1 = fmaf(b2f_hi(r.x), nm, a1);
            a2 = fmaf(b2f_lo(r.y), nm, a2);
            a3 = fmaf(b2f_hi(r.y), nm, a3);
        }
        if (e2 < m) {
            int2 p = ep[e2];
            uint2 r = *(const uint2*)(g + (size_t)p.x * 64 + t * 4);
            float nm = __int_as_float(p.y);
            a0 = fmaf(b2f_lo(r.x), nm, a0);
            a1 = fmaf(b2f_hi(r.x), nm, a1);
            a2 = fmaf(b2f_lo(r.y), nm, a2);
            a3 = fmaf(b2f_hi(r.y), nm, a3);
        }
    }
    // sum the 4 quarters
    a0 += __shfl_xor(a0, 16); a0 += __shfl_xor(a0, 32);
    a1 += __shfl_xor(a1, 16); a1 += __shfl_xor(a1, 32);
    a2 += __shfl_xor(a2, 16); a2 += __shfl_xor(a2, 32);
    a3 += __shfl_xor(a3, 16); a3 += __shfl_xor(a3, 32);
    if (q != 0) return;
    // self-loop (weight 1 on g), then scale by dinv[node], bias, store
    uint2 sr = *(const uint2*)(g + (size_t)node * 64 + t * 4);
    a0 += b2f_lo(sr.x); a1 += b2f_hi(sr.x);
    a2 += b2f_lo(sr.y); a3 += b2f_hi(sr.y);
    float di = dinv[node];
    a0 *= di; a1 *= di; a2 *= di; a3 *= di;
    if (!SPLIT_OUT) {
        float4 bb = ld4(bias0 + t * 4);
        a0 += bb.x; a1 += bb.y; a2 += bb.z; a3 += bb.w;
        if (RELU) {
            a0 = fmaxf(a0, 0.f); a1 = fmaxf(a1, 0.f);
            a2 = fmaxf(a2, 0.f); a3 = fmaxf(a3, 0.f);
        }
        ushort4 u = make_ushort4(f2b(a0), f2b(a1), f2b(a2), f2b(a3));
        *(ushort4*)((unsigned short*)outv + (size_t)node * 64 + t * 4) = u;
    } else {
        float* out = (float*)outv;
        if (t < 8) {
            float4 bb = ld4(bias0 + t * 4);
            float4 v = make_float4(a0 + bb.x, a1 + bb.y, a2 + bb.z, a3 + bb.w);
            *(float4*)&out[(size_t)node * 32 + t * 4] = v;
        } else {
            float4 bb = ld4(bias1 + (t - 8) * 4);
            float4 v = make_float4(a0 + bb.x, a1 + bb.y, a2 + bb.z, a3 + bb.w);
            *(float4*)&out[(size_t)n * 32 + (size_t)node * 32 + (t - 8) * 4] = v;
        }
    }
}

// -------------------- launch --------------------
extern "C" void kernel_launch(void* const* d_in, const int* in_sizes, int n_in,
                              void* d_out, int out_size, void* d_ws, size_t ws_size,
                              hipStream_t stream) {
    const float* x   = (const float*)d_in[0];
    const int*   ei  = (const int*)d_in[1];   // [2, E]
    const float* ew  = (const float*)d_in[2];
    const float* W1  = (const float*)d_in[3];
    const float* b1  = (const float*)d_in[4];
    const float* Wmu = (const float*)d_in[5];
    const float* bmu = (const float*)d_in[6];
    const float* Wlv = (const float*)d_in[7];
    const float* blv = (const float*)d_in[8];
    float* outp = (float*)d_out;

    const int n = in_sizes[0] / 128;
    const int E = in_sizes[2];
    const int* src = ei;
    const int* dst = ei + E;
    const int NB = (n + NPB - 1) / NPB;            // bins of 512 nodes
    const int capE = E / NB + 2048;                // uniform dst: mean E/NB + slack

    // workspace layout
    size_t o = 0;
    auto alloc = [&](size_t bytes) { void* p = (char*)d_ws + o; o += (bytes + 511) & ~(size_t)511; return p; };
    int*   bin_cnt  = (int*)alloc((size_t)NB * 4);                 // memset 0
    int2*  rowcnt   = (int2*)alloc((size_t)n * 8);
    float* dinv     = (float*)alloc((size_t)n * 4);
    unsigned long long* csr  = (unsigned long long*)alloc((size_t)E * 8);
    unsigned long long* ebuf = (unsigned long long*)alloc((size_t)NB * capE * 8);
    unsigned short* g0 = (unsigned short*)alloc((size_t)n * 64 * 2);   // bf16, dinv-scaled
    unsigned short* h  = (unsigned short*)alloc((size_t)n * 64 * 2);   // bf16 (plain hidden)
    unsigned short* g2 = g0;   // gemm2 output reuses g0 (dead after prop1)

    hipMemsetAsync(bin_cnt, 0, (size_t)NB * 4, stream);
    k_bin<<<(E + 4095) / 4096, 1024, NB * 2 * sizeof(int), stream>>>(src, dst, ew, bin_cnt,
                                                                     ebuf, E, capE, NB);
    k_csr_build<<<NB, 512, 0, stream>>>(ebuf, bin_cnt, rowcnt, dinv, csr, n, capE);

    const int gb = (n + 63) / 64;
    k_gemm<128, false, false><<<gb, 256, 0, stream>>>(x, W1, nullptr, dinv, g0, n);
    k_prop<true, false><<<(n + 3) / 4, 256, 0, stream>>>(g0, (const int2*)csr, rowcnt, dinv,
                                                         b1, nullptr, h, n);
    k_gemm<64, true, true><<<gb, 256, 0, stream>>>(h, Wmu, Wlv, dinv, g2, n);
    k_prop<false, true><<<(n + 3) / 4, 256, 0, stream>>>(g2, (const int2*)csr, rowcnt, dinv,
                                                         bmu, blv, outp, n);
}

// Round 9
// 318.970 us; speedup vs baseline: 1.7444x; 1.0606x over previous
//
#include <hip/hip_runtime.h>

// -------------------- helpers --------------------
static __device__ __forceinline__ float4 ld4(const float* p) { return *(const float4*)p; }
static __device__ __forceinline__ float b2f(unsigned short u) {
    return __uint_as_float((unsigned)u << 16);
}
static __device__ __forceinline__ float b2f_lo(unsigned u) { return __uint_as_float(u << 16); }
static __device__ __forceinline__ float b2f_hi(unsigned u) { return __uint_as_float(u & 0xFFFF0000u); }
static __device__ __forceinline__ unsigned short f2b(float f) {   // round-to-nearest-even
    unsigned x = __float_as_uint(f);
    return (unsigned short)((x + 0x7FFFu + ((x >> 16) & 1u)) >> 16);
}

#define NPB 256              // nodes per bin (pow2: ld = d & 255, bin = d >> 8)
#define CAPE 5120            // per-bin edge capacity (mean 4092, sigma 64 -> 16 sigma slack)

// math: out[d] = dinv[d]*( g[d] + sum_e ew_e * g[src_e] ) + bias,  g = dinv (.) h
// CSR stores (src, raw ew); dinv folded into gemm epilogue and prop epilogue.

// ==================== fused kernel 1: gemm1 (x@W1 -> g0) + edge binning ====================
// blocks [0, gb): 64x64 gemm tile, K=128 in two 64-chunks (32 KB LDS).
// blocks [gb, gb+bb): bin 4096 edges by dst>>8 into ebuf segments (packed u64).
// packed entry: [ew:32][ld:8][src:17]
__global__ __launch_bounds__(256) void k_fused1(const float* __restrict__ A,
                                                const float* __restrict__ W0,
                                                const float* __restrict__ dinv_unused,
                                                unsigned short* __restrict__ gout,
                                                const int* __restrict__ src,
                                                const int* __restrict__ dst,
                                                const float* __restrict__ ew,
                                                int* __restrict__ bin_cnt,
                                                unsigned long long* __restrict__ ebuf,
                                                int n, int E, int gb, int NB) {
    __shared__ float Ws[64 * 64];     // 16 KB (also covers bin path's needs below)
    __shared__ float Xs[64 * 64];     // 16 KB
    __shared__ int hist[512];
    __shared__ int hbase[512];
    int tid = threadIdx.x;

    if ((int)blockIdx.x < gb) {
        // ---------------- gemm1 path: g0 = (x @ W1), scaled later by prop (no dinv here yet)
        int row0 = blockIdx.x * 64;
        int c0 = (tid & 15) * 4;
        int r0 = (tid >> 4) * 4;
        float4 acc[4] = {};
        #pragma unroll
        for (int p = 0; p < 2; p++) {
            // stage W chunk: rows p*64..p*64+63 (linear 4096 floats)
            for (int j = tid; j < 1024; j += 256)
                *(float4*)&Ws[j * 4] = ld4(W0 + p * 4096 + j * 4);
            // stage X chunk: 64 rows x 64 k
            for (int j = tid; j < 1024; j += 256) {
                int r = j >> 4, kc = j & 15;
                int grow = row0 + r;
                float4 v = make_float4(0.f, 0.f, 0.f, 0.f);
                if (grow < n) v = ld4(A + (size_t)grow * 128 + p * 64 + kc * 4);
                *(float4*)&Xs[r * 64 + kc * 4] = v;
            }
            __syncthreads();
            #pragma unroll 4
            for (int kk = 0; kk < 64; kk += 4) {
                float4 w0 = ld4(&Ws[(kk + 0) * 64 + c0]);
                float4 w1 = ld4(&Ws[(kk + 1) * 64 + c0]);
                float4 w2 = ld4(&Ws[(kk + 2) * 64 + c0]);
                float4 w3 = ld4(&Ws[(kk + 3) * 64 + c0]);
                #pragma unroll
                for (int i = 0; i < 4; i++) {
                    float4 a = ld4(&Xs[(r0 + i) * 64 + kk]);
                    acc[i].x = fmaf(a.x, w0.x, fmaf(a.y, w1.x, fmaf(a.z, w2.x, fmaf(a.w, w3.x, acc[i].x))));
                    acc[i].y = fmaf(a.x, w0.y, fmaf(a.y, w1.y, fmaf(a.z, w2.y, fmaf(a.w, w3.y, acc[i].y))));
                    acc[i].z = fmaf(a.x, w0.z, fmaf(a.y, w1.z, fmaf(a.z, w2.z, fmaf(a.w, w3.z, acc[i].z))));
                    acc[i].w = fmaf(a.x, w0.w, fmaf(a.y, w1.w, fmaf(a.z, w2.w, fmaf(a.w, w3.w, acc[i].w))));
                }
            }
            __syncthreads();
        }
        // NOTE: dinv is NOT ready yet (built concurrently) -> store plain h in bf16;
        // prop1 reads g implicitly scaled: we instead fold dinv into prop1's edge weight? No —
        // we store plain h here and apply dinv-scaling inside prop via gather of... 
        // Correction: keep original scheme — gemm1 must not need dinv. We store h (unscaled);
        // prop1 uses csr norm built WITH dinv (see k_csr_build: it stores dinv[src]*ew*dinv... no).
        // Resolution: store h unscaled; prop template multiplies gathered rows by nothing but
        // the csr weight, which for prop1 we make norm-complete. See k_csr_build: csr stores
        // (src, ew) raw; prop needs g=dinv*h. So prop1 loads h and needs dinv[src] — NO.
        // => we keep a separate tiny kernel k_scale that applies dinv to h0 after build. 
        #pragma unroll
        for (int i = 0; i < 4; i++) {
            int grow = row0 + r0 + i;
            if (grow < n) {
                ushort4 u = make_ushort4(f2b(acc[i].x), f2b(acc[i].y), f2b(acc[i].z), f2b(acc[i].w));
                *(ushort4*)&gout[(size_t)grow * 64 + c0] = u;
            }
        }
    } else {
        // ---------------- bin path: 4096 edges
        for (int j = tid; j < NB; j += 256) hist[j] = 0;
        __syncthreads();
        int e0 = ((int)blockIdx.x - gb) * 4096;
        unsigned long long pk[16]; int bb[16]; int loc[16];
        #pragma unroll
        for (int j = 0; j < 16; j++) {
            int e = e0 + j * 256 + tid;
            if (e < E) {
                int s = src[e];
                int d = dst[e];
                float w = ew[e];
                bb[j] = d >> 8;
                pk[j] = ((unsigned long long)__float_as_uint(w) << 32) |
                        (unsigned)((d & (NPB - 1)) << 17) | (unsigned)s;
                loc[j] = atomicAdd(&hist[bb[j]], 1);
            } else bb[j] = -1;
        }
        __syncthreads();
        for (int j = tid; j < NB; j += 256) hbase[j] = atomicAdd(&bin_cnt[j], hist[j]);
        __syncthreads();
        #pragma unroll
        for (int j = 0; j < 16; j++) {
            if (bb[j] >= 0)
                ebuf[(size_t)bb[j] * CAPE + hbase[bb[j]] + loc[j]] = pk[j];
        }
    }
}

// ==================== pass 2: per-bin LDS-resident count+scan+scatter ====================
__global__ __launch_bounds__(512) void k_csr_build(const unsigned long long* __restrict__ ebuf,
                                                   const int* __restrict__ bin_cnt,
                                                   int2* __restrict__ rowcnt,
                                                   float* __restrict__ dinv,
                                                   unsigned long long* __restrict__ csr,
                                                   int n) {
    __shared__ unsigned long long eL[CAPE];   // 40 KB
    __shared__ unsigned cntL[NPB];
    __shared__ unsigned ewsL[NPB];
    __shared__ unsigned fillL[NPB];
    __shared__ int scanL[512];
    __shared__ int rowL[NPB];
    __shared__ int binbase_s;
    int b = blockIdx.x;
    int tid = threadIdx.x;
    if (tid < NPB) { cntL[tid] = 0; ewsL[tid] = 0; fillL[tid] = 0; }
    scanL[tid] = (tid < b) ? bin_cnt[tid] : 0;
    __syncthreads();
    int m = bin_cnt[b];
    const unsigned long long* eb = ebuf + (size_t)b * CAPE;
    for (int i = tid; i < m; i += 512) {
        unsigned long long pk = eb[i];
        eL[i] = pk;
        int ld = (int)((pk >> 17) & (NPB - 1));
        float w = __uint_as_float((unsigned)(pk >> 32));
        atomicAdd(&cntL[ld], 1u);
        atomicAdd(&ewsL[ld], (unsigned)(w * 16777216.0f));   // 2^24 fixed point
    }
    __syncthreads();
    // bin base = sum of bin_cnt[0..b)
    #pragma unroll
    for (int off = 256; off > 0; off >>= 1) {
        if (tid < off) scanL[tid] += scanL[tid + off];
        __syncthreads();
    }
    if (tid == 0) binbase_s = scanL[0];
    __syncthreads();
    // exclusive prefix over cntL (512-wide, entries >= NPB are zero)
    int v = (tid < NPB) ? (int)cntL[tid] : 0;
    scanL[tid] = v;
    __syncthreads();
    #pragma unroll
    for (int off = 1; off < 512; off <<= 1) {
        int t = (tid >= off) ? scanL[tid - off] : 0;
        __syncthreads();
        scanL[tid] += t;
        __syncthreads();
    }
    if (tid < NPB) {
        int rp = binbase_s + scanL[tid] - v;
        rowL[tid] = rp;
        int node = b * NPB + tid;
        if (node < n) {
            rowcnt[node] = make_int2(rp, v);
            dinv[node] = rsqrtf(1.0f + (float)ewsL[tid] * (1.0f / 16777216.0f));
        }
    }
    __syncthreads();
    // scatter from LDS; csr entry = (src, raw ew)
    for (int i = tid; i < m; i += 512) {
        unsigned long long pk = eL[i];
        int s = (int)(pk & 0x1FFFF);
        int ld = (int)((pk >> 17) & (NPB - 1));
        int pos = rowL[ld] + (int)atomicAdd(&fillL[ld], 1u);
        csr[pos] = (unsigned long long)(unsigned)s | (pk & 0xFFFFFFFF00000000ull);
    }
}

// ==================== scale h0 (bf16) by dinv -> g0 in place ====================
__global__ __launch_bounds__(256) void k_scale(unsigned short* __restrict__ h0,
                                               const float* __restrict__ dinv, int n) {
    int i = blockIdx.x * 256 + threadIdx.x;   // one thread per 4 channels: n*16 threads
    if (i >= n * 16) return;
    int node = i >> 4;
    float sc = dinv[node];
    ushort4 u = *(ushort4*)&h0[(size_t)i * 4];
    u = make_ushort4(f2b(b2f(u.x) * sc), f2b(b2f(u.y) * sc),
                     f2b(b2f(u.z) * sc), f2b(b2f(u.w) * sc));
    *(ushort4*)&h0[(size_t)i * 4] = u;
}

// ==================== GEMM (standalone, used for layer 2): g = dinv (.) (A @ [Wmu|Wlv]) ======
template<int K, bool SPLITW, bool ABF16>
__global__ __launch_bounds__(256) void k_gemm(const void* __restrict__ Av,
                                              const float* __restrict__ W0,
                                              const float* __restrict__ W1s,
                                              const float* __restrict__ dinv,
                                              unsigned short* __restrict__ out, int n) {
    __shared__ float Ws[K * 64];
    __shared__ float Xs[64 * K];
    int tid = threadIdx.x;
    int row0 = blockIdx.x * 64;

    constexpr int WF4 = K * 64 / 4;
    for (int j = tid; j < WF4; j += 256) {
        float4 v;
        if (!SPLITW) {
            v = ld4(W0 + j * 4);
        } else {
            int k = (j * 4) >> 6;
            int c = (j * 4) & 63;
            v = (c < 32) ? ld4(W0 + k * 32 + c) : ld4(W1s + k * 32 + (c - 32));
        }
        *(float4*)&Ws[j * 4] = v;
    }
    constexpr int XF4PR = K / 4;
    for (int j = tid; j < 64 * XF4PR; j += 256) {
        int r = j / XF4PR, kc = j % XF4PR;
        int grow = row0 + r;
        float4 v = make_float4(0.f, 0.f, 0.f, 0.f);
        if (grow < n) {
            if (ABF16) {
                const unsigned short* Ab = (const unsigned short*)Av;
                ushort4 u = *(const ushort4*)(Ab + (size_t)grow * K + kc * 4);
                v = make_float4(b2f(u.x), b2f(u.y), b2f(u.z), b2f(u.w));
            } else {
                v = ld4((const float*)Av + (size_t)grow * K + kc * 4);
            }
        }
        *(float4*)&Xs[r * K + kc * 4] = v;
    }
    __syncthreads();

    int c0 = (tid & 15) * 4;
    int r0 = (tid >> 4) * 4;
    float4 acc[4] = {};
    #pragma unroll 4
    for (int kk = 0; kk < K; kk += 4) {
        float4 w0 = ld4(&Ws[(kk + 0) * 64 + c0]);
        float4 w1 = ld4(&Ws[(kk + 1) * 64 + c0]);
        float4 w2 = ld4(&Ws[(kk + 2) * 64 + c0]);
        float4 w3 = ld4(&Ws[(kk + 3) * 64 + c0]);
        #pragma unroll
        for (int i = 0; i < 4; i++) {
            float4 a = ld4(&Xs[(r0 + i) * K + kk]);
            acc[i].x = fmaf(a.x, w0.x, fmaf(a.y, w1.x, fmaf(a.z, w2.x, fmaf(a.w, w3.x, acc[i].x))));
            acc[i].y = fmaf(a.x, w0.y, fmaf(a.y, w1.y, fmaf(a.z, w2.y, fmaf(a.w, w3.y, acc[i].y))));
            acc[i].z = fmaf(a.x, w0.z, fmaf(a.y, w1.z, fmaf(a.z, w2.z, fmaf(a.w, w3.z, acc[i].z))));
            acc[i].w = fmaf(a.x, w0.w, fmaf(a.y, w1.w, fmaf(a.z, w2.w, fmaf(a.w, w3.w, acc[i].w))));
        }
    }
    #pragma unroll
    for (int i = 0; i < 4; i++) {
        int grow = row0 + r0 + i;
        if (grow < n) {
            float sc = dinv[grow];
            ushort4 u = make_ushort4(f2b(acc[i].x * sc), f2b(acc[i].y * sc),
                                     f2b(acc[i].z * sc), f2b(acc[i].w * sc));
            *(ushort4*)&out[(size_t)grow * 64 + c0] = u;
        }
    }
}

// -------------------- propagation: one wave per node, 4 edges per VMEM instruction ----------
// g is dinv-scaled; csr = (src, raw ew). out = dinv[d]*(g[d] + sum w*g[s]) + bias.
template<bool RELU, bool SPLIT_OUT>
__global__ __launch_bounds__(256) void k_prop(const unsigned short* __restrict__ g,
                                              const int2* __restrict__ csr,
                                              const int2* __restrict__ rowcnt,
                                              const float* __restrict__ dinv,
                                              const float* __restrict__ bias0,
                                              const float* __restrict__ bias1,
                                              void* __restrict__ outv, int n) {
    int node = blockIdx.x * 4 + (threadIdx.x >> 6);
    if (node >= n) return;
    int lane = threadIdx.x & 63;
    int q = lane >> 4;          // quarter: edge slot
    int t = lane & 15;          // sub-lane: channel quad 4t..4t+3
    float a0 = 0.f, a1 = 0.f, a2 = 0.f, a3 = 0.f;
    int2 rc = rowcnt[node];
    const int2* ep = csr + rc.x;
    int m = rc.y;
    for (int e = 0; e < m; e += 8) {
        int e1 = e + q, e2 = e + 4 + q;
        if (e1 < m) {
            int2 p = ep[e1];
            uint2 r = *(const uint2*)(g + (size_t)p.x * 64 + t * 4);
            float nm = __int_as_float(p.y);
            a0 = fmaf(b2f_lo(r.x), nm, a0);
            a1 = fmaf(b2f_hi(r.x), nm, a1);
            a2 = fmaf(b2f_lo(r.y), nm, a2);
            a3 = fmaf(b2f_hi(r.y), nm, a3);
        }
        if (e2 < m) {
            int2 p = ep[e2];
            uint2 r = *(const uint2*)(g + (size_t)p.x * 64 + t * 4);
            float nm = __int_as_float(p.y);
            a0 = fmaf(b2f_lo(r.x), nm, a0);
            a1 = fmaf(b2f_hi(r.x), nm, a1);
            a2 = fmaf(b2f_lo(r.y), nm, a2);
            a3 = fmaf(b2f_hi(r.y), nm, a3);
        }
    }
    a0 += __shfl_xor(a0, 16); a0 += __shfl_xor(a0, 32);
    a1 += __shfl_xor(a1, 16); a1 += __shfl_xor(a1, 32);
    a2 += __shfl_xor(a2, 16); a2 += __shfl_xor(a2, 32);
    a3 += __shfl_xor(a3, 16); a3 += __shfl_xor(a3, 32);
    if (q != 0) return;
    uint2 sr = *(const uint2*)(g + (size_t)node * 64 + t * 4);
    a0 += b2f_lo(sr.x); a1 += b2f_hi(sr.x);
    a2 += b2f_lo(sr.y); a3 += b2f_hi(sr.y);
    float di = dinv[node];
    a0 *= di; a1 *= di; a2 *= di; a3 *= di;
    if (!SPLIT_OUT) {
        float4 bb = ld4(bias0 + t * 4);
        a0 += bb.x; a1 += bb.y; a2 += bb.z; a3 += bb.w;
        if (RELU) {
            a0 = fmaxf(a0, 0.f); a1 = fmaxf(a1, 0.f);
            a2 = fmaxf(a2, 0.f); a3 = fmaxf(a3, 0.f);
        }
        ushort4 u = make_ushort4(f2b(a0), f2b(a1), f2b(a2), f2b(a3));
        *(ushort4*)((unsigned short*)outv + (size_t)node * 64 + t * 4) = u;
    } else {
        float* out = (float*)outv;
        if (t < 8) {
            float4 bb = ld4(bias0 + t * 4);
            float4 v = make_float4(a0 + bb.x, a1 + bb.y, a2 + bb.z, a3 + bb.w);
            *(float4*)&out[(size_t)node * 32 + t * 4] = v;
        } else {
            float4 bb = ld4(bias1 + (t - 8) * 4);
            float4 v = make_float4(a0 + bb.x, a1 + bb.y, a2 + bb.z, a3 + bb.w);
            *(float4*)&out[(size_t)n * 32 + (size_t)node * 32 + (t - 8) * 4] = v;
        }
    }
}

// -------------------- launch --------------------
extern "C" void kernel_launch(void* const* d_in, const int* in_sizes, int n_in,
                              void* d_out, int out_size, void* d_ws, size_t ws_size,
                              hipStream_t stream) {
    const float* x   = (const float*)d_in[0];
    const int*   ei  = (const int*)d_in[1];   // [2, E]
    const float* ew  = (const float*)d_in[2];
    const float* W1  = (const float*)d_in[3];
    const float* b1  = (const float*)d_in[4];
    const float* Wmu = (const float*)d_in[5];
    const float* bmu = (const float*)d_in[6];
    const float* Wlv = (const float*)d_in[7];
    const float* blv = (const float*)d_in[8];
    float* outp = (float*)d_out;

    const int n = in_sizes[0] / 128;
    const int E = in_sizes[2];
    const int* src = ei;
    const int* dst = ei + E;
    const int NB = (n + NPB - 1) / NPB;            // bins of 256 nodes (391)

    // workspace layout
    size_t o = 0;
    auto alloc = [&](size_t bytes) { void* p = (char*)d_ws + o; o += (bytes + 511) & ~(size_t)511; return p; };
    int*   bin_cnt  = (int*)alloc((size_t)NB * 4);                 // memset 0
    int2*  rowcnt   = (int2*)alloc((size_t)n * 8);
    float* dinv     = (float*)alloc((size_t)n * 4);
    unsigned long long* csr  = (unsigned long long*)alloc((size_t)E * 8);
    unsigned long long* ebuf = (unsigned long long*)alloc((size_t)NB * CAPE * 8);
    unsigned short* g0 = (unsigned short*)alloc((size_t)n * 64 * 2);   // bf16
    unsigned short* h  = (unsigned short*)alloc((size_t)n * 64 * 2);   // bf16
    unsigned short* g2 = g0;   // gemm2 output reuses g0 (dead after prop1)

    const int gb = (n + 63) / 64;                  // gemm blocks (1563)
    const int bb = (E + 4095) / 4096;              // bin blocks (391)

    hipMemsetAsync(bin_cnt, 0, (size_t)NB * 4, stream);
    k_fused1<<<gb + bb, 256, 0, stream>>>(x, W1, nullptr, g0, src, dst, ew,
                                          bin_cnt, ebuf, n, E, gb, NB);
    k_csr_build<<<NB, 512, 0, stream>>>(ebuf, bin_cnt, rowcnt, dinv, csr, n);
    k_scale<<<(n * 16 + 255) / 256, 256, 0, stream>>>(g0, dinv, n);
    k_prop<true, false><<<(n + 3) / 4, 256, 0, stream>>>(g0, (const int2*)csr, rowcnt, dinv,
                                                         b1, nullptr, h, n);
    k_gemm<64, true, true><<<gb, 256, 0, stream>>>(h, Wmu, Wlv, dinv, g2, n);
    k_prop<false, true><<<(n + 3) / 4, 256, 0, stream>>>(g2, (const int2*)csr, rowcnt, dinv,
                                                         bmu, blv, outp, n);
}